// Round 8
// baseline (789.762 us; speedup 1.0000x reference)
//
#include <hip/hip_runtime.h>
#include <hip/hip_bf16.h>
#include <math.h>

#define NN 50000
#define NE 100000
#define FN 128
#define FE 16
#define HD 64
#define OUTD 32
#define NG 64
#define ZK 65           // 64 edge-MLP features + 1 bias slot (z=1)
#define KPARTS 4        // K-split: 17+16+16+16 slabs

typedef unsigned int uint;
typedef unsigned short ushort;
typedef __attribute__((ext_vector_type(8))) short short8;
typedef __attribute__((ext_vector_type(16))) float f32x16;

static __device__ __forceinline__ float bfbits2f(uint u) {
    return __builtin_bit_cast(float, u << 16);
}
// one v_perm_b32: result = (hi16(f1)<<16) | hi16(f0)   (truncation pack)
static __device__ __forceinline__ uint packbf(float f0, float f1) {
    return __builtin_amdgcn_perm(__builtin_bit_cast(uint, f1),
                                 __builtin_bit_cast(uint, f0), 0x07060302u);
}
static __device__ __forceinline__ ushort f2bf(float f) {
    uint u = __builtin_bit_cast(uint, f);
    u = (u + 0x7FFFu + ((u >> 16) & 1u)) >> 16;   // RNE
    return (ushort)u;
}
static __device__ __forceinline__ uint pack2rne(float f0, float f1) {
    return (uint)f2bf(f0) | ((uint)f2bf(f1) << 16);
}
static __device__ __forceinline__ float fsigmoid(float x) {
    return 1.f / (1.f + __expf(-x));
}
static __device__ __forceinline__ float ftanh(float x) {
    float t = __expf(2.f * x);
    return 1.f - 2.f / (t + 1.f);
}

// ---- prep: Wtb (message B, k0-blocked) + Bgru ----
#define PREP_S0 (ZK * 4096)
#define PREP_S1 (256 * 128)
__global__ void k_prep(const float* __restrict__ W_e2, const float* __restrict__ b_e2,
                       const float* __restrict__ W_ih, const float* __restrict__ W_hh,
                       ushort* __restrict__ Wtb, ushort* __restrict__ Bg) {
    int idx = blockIdx.x * 256 + threadIdx.x;
    if (idx < PREP_S0) {
        int k0 = idx >> 12, r = idx & 4095;
        int i = r >> 6, j = r & 63;
        float v = (k0 < 64) ? W_e2[k0 * 4096 + i * 64 + j] : b_e2[i * 64 + j];
        Wtb[idx] = f2bf(v);
        return;
    }
    idx -= PREP_S0;
    if (idx < PREP_S1) {
        int n = idx >> 7, k = idx & 127;
        int g = n >> 6, i = n & 63;
        float v = 0.f;
        if (g == 0)      v = (k < 64) ? W_ih[i * 64 + k]         : W_hh[i * 64 + (k - 64)];
        else if (g == 1) v = (k < 64) ? W_ih[(64 + i) * 64 + k]  : W_hh[(64 + i) * 64 + (k - 64)];
        else if (g == 2) v = (k < 64) ? W_ih[(128 + i) * 64 + k] : 0.f;
        else             v = (k < 64) ? 0.f                      : W_hh[(128 + i) * 64 + (k - 64)];
        Bg[idx] = f2bf(v);
    }
}

// ---- merged encoder + edge-MLP (grid split on blockIdx.x) ----
#define NBENC ((NN + 127) / 128)
#define NBEDG ((NE + 255) / 256)
__global__ __launch_bounds__(256, 2)
void k_enc_edge(const float* __restrict__ x, const float* __restrict__ W_enc,
                const float* __restrict__ b_enc,
                const float* __restrict__ ea, const float* __restrict__ W_e1,
                const float* __restrict__ b_e1,
                float* __restrict__ h, ushort* __restrict__ hb,
                ushort* __restrict__ zbT) {
    int t = threadIdx.x;
    if (blockIdx.x < NBENC) {
        // ---- encoder: h = x @ W_enc + b_enc.  M=50000, K=128, N=64 ----
        __shared__ __align__(16) ushort blds[64 * 128];   // 16 KB, XOR-swizzled slots
        int wave = t >> 6, lane = t & 63, l31 = lane & 31, lhi = lane >> 5;
        for (int idx = t; idx < 1024; idx += 256) {       // 1024 slots of 16B
            int n = idx >> 4, p = idx & 15;
            int ssrc = p ^ (n & 15);
            int kk = ssrc * 8;                            // W_enc[k][n], k=kk..kk+7 -> bf16
            uint4 u;
            u.x = pack2rne(W_enc[(kk + 0) * 64 + n], W_enc[(kk + 1) * 64 + n]);
            u.y = pack2rne(W_enc[(kk + 2) * 64 + n], W_enc[(kk + 3) * 64 + n]);
            u.z = pack2rne(W_enc[(kk + 4) * 64 + n], W_enc[(kk + 5) * 64 + n]);
            u.w = pack2rne(W_enc[(kk + 6) * 64 + n], W_enc[(kk + 7) * 64 + n]);
            *(uint4*)&blds[idx * 8] = u;
        }
        int node0 = blockIdx.x * 128 + wave * 32;
        int m = node0 + l31;
        int mc = (m < NN) ? m : NN - 1;
        short8 afr[8];
        const float* xr = x + (size_t)mc * 128;
        #pragma unroll
        for (int ks = 0; ks < 8; ks++) {
            float4 v0 = *(const float4*)(xr + ks * 16 + lhi * 8);
            float4 v1 = *(const float4*)(xr + ks * 16 + lhi * 8 + 4);
            uint4 u;
            u.x = pack2rne(v0.x, v0.y); u.y = pack2rne(v0.z, v0.w);
            u.z = pack2rne(v1.x, v1.y); u.w = pack2rne(v1.z, v1.w);
            afr[ks] = __builtin_bit_cast(short8, u);
        }
        __syncthreads();
        #pragma unroll
        for (int ct = 0; ct < 2; ct++) {
            f32x16 acc = {0};
            int n = ct * 32 + l31;
            #pragma unroll
            for (int ks = 0; ks < 8; ks++) {
                int sp = (ks * 2 + lhi) ^ (n & 15);
                short8 bf = *(const short8*)&blds[n * 128 + sp * 8];
                acc = __builtin_amdgcn_mfma_f32_32x32x16_bf16(afr[ks], bf, acc, 0, 0, 0);
            }
            int o = ct * 32 + l31;
            float bias = b_enc[o];
            #pragma unroll
            for (int r = 0; r < 16; r++) {
                int row = (r & 3) + 8 * (r >> 2) + 4 * lhi;
                int node = node0 + row;
                if (node < NN) {
                    float v = acc[r] + bias;
                    h[node * 64 + o] = v;
                    hb[node * 64 + o] = f2bf(v);
                }
            }
        }
    } else {
        // ---- edge MLP: one thread per edge, all 64 outputs; zbT[k][e] ----
        __shared__ float Ws[16 * 64];
        __shared__ float b1s[64];
        for (int idx = t; idx < 1024; idx += 256) Ws[idx] = W_e1[idx];
        if (t < 64) b1s[t] = b_e1[t];
        __syncthreads();
        int e = (blockIdx.x - NBENC) * 256 + t;
        int ec = (e < NE) ? e : NE - 1;
        float eav[16];
        const float4* ep = (const float4*)(ea + ec * 16);
        #pragma unroll
        for (int q = 0; q < 4; q++) {
            float4 v = ep[q];
            eav[q * 4 + 0] = v.x; eav[q * 4 + 1] = v.y; eav[q * 4 + 2] = v.z; eav[q * 4 + 3] = v.w;
        }
        if (e >= NE) return;
        #pragma unroll 4
        for (int k = 0; k < 64; k++) {
            float acc = b1s[k];
            #pragma unroll
            for (int f = 0; f < 16; f++) acc += eav[f] * Ws[f * 64 + k];
            zbT[(size_t)k * NE + e] = f2bf(fmaxf(acc, 0.f));
        }
        zbT[(size_t)64 * NE + e] = f2bf(1.0f);
    }
}

// ---- MFMA message kernel: K-split x4, stage-once, barrier-free K-loop ----
// Block = 256 edges x 4 waves (wave = 64 edges), blockIdx.y = K-part (16-17 slabs).
// Prologue: stage ALL part slabs (<=136KB) into LDS + gather h + preload ALL z into
// registers; ONE barrier. K-loop reads only LDS/registers -> no barrier drains at all.
// 1 block/CU (LDS-bound) is fine: no stalls left to hide.
__global__ __launch_bounds__(256, 1)
void k_message(const ushort* __restrict__ zbT, const ushort* __restrict__ hb,
               const int* __restrict__ eidx, const ushort* __restrict__ Wtb,
               float* __restrict__ m_agg) {
    __shared__ __align__(16) ushort wlds[17 * 4096];   // 136 KB max
    __shared__ int sdst[256];

    int t = threadIdx.x;
    int wave = t >> 6, lane = t & 63;
    int l31 = lane & 31, lhi = lane >> 5;
    int eblk = blockIdx.x * 256;
    int e0 = eblk + wave * 64;
    int part = blockIdx.y;
    int kbeg = (part == 0) ? 0 : (16 * part + 1);      // 0,17,33,49
    int knum = (part == 0) ? 17 : 16;

    {
        int e = eblk + t; if (e >= NE) e = NE - 1;
        sdst[t] = eidx[NE + e];
    }

    // stage knum slabs: slot = call*256 + t, 16B each, XOR-swizzled within rows
    for (int call = 0; call < knum * 2; call++) {
        int slot = call * 256 + t;
        int slab = slot >> 9, w = slot & 511;
        int i = w >> 3, jbp = w & 7;
        int jbg = jbp ^ (i & 7);
        const ushort* src = Wtb + (size_t)(kbeg + slab) * 4096 + i * 64 + jbg * 8;
        __builtin_amdgcn_global_load_lds(
            (const __attribute__((address_space(1))) void*)src,
            (__attribute__((address_space(3))) void*)&wlds[(size_t)(call * 256 + wave * 64) * 8],
            16, 0, 0);
    }

    // gather h fragments (fp32 in regs)
    float hf[2][32];
    #pragma unroll
    for (int mt = 0; mt < 2; mt++) {
        int e = e0 + mt * 32 + l31;
        int ec = (e < NE) ? e : NE - 1;
        int s = eidx[ec];
        const ushort* hrow = hb + (size_t)s * 64;
        #pragma unroll
        for (int c = 0; c < 4; c++) {
            uint4 v = *(const uint4*)(hrow + c * 16 + lhi * 8);
            hf[mt][c * 8 + 0] = bfbits2f(v.x & 0xFFFFu); hf[mt][c * 8 + 1] = bfbits2f(v.x >> 16);
            hf[mt][c * 8 + 2] = bfbits2f(v.y & 0xFFFFu); hf[mt][c * 8 + 3] = bfbits2f(v.y >> 16);
            hf[mt][c * 8 + 4] = bfbits2f(v.z & 0xFFFFu); hf[mt][c * 8 + 5] = bfbits2f(v.z >> 16);
            hf[mt][c * 8 + 6] = bfbits2f(v.w & 0xFFFFu); hf[mt][c * 8 + 7] = bfbits2f(v.w >> 16);
        }
    }

    // preload ALL z for this part into registers (static indexing -> no spill)
    float zf[17][2];
    #pragma unroll
    for (int kk = 0; kk < 17; kk++) {
        #pragma unroll
        for (int mt = 0; mt < 2; mt++) {
            int e = e0 + mt * 32 + l31;
            zf[kk][mt] = (kk < knum && e < NE)
                ? bfbits2f((uint)zbT[(size_t)(kbeg + kk) * NE + e]) : 0.f;
        }
    }

    __syncthreads();   // the ONE barrier: slabs + (z,h already in regs) ready

    f32x16 acc00 = {0}, acc01 = {0}, acc10 = {0}, acc11 = {0};

    #pragma unroll
    for (int kk = 0; kk < 17; kk++) {
        if (kk >= knum) break;                        // uniform; avoids stale-slab NaN
        const ushort* wb = &wlds[(size_t)kk * 4096];
        float zf0 = zf[kk][0], zf1 = zf[kk][1];
        #pragma unroll
        for (int c = 0; c < 4; c++) {
            int jb = c * 2 + lhi;
            short8 b0 = *(const short8*)&wb[((0 * 32 + l31) << 6) + ((jb ^ (l31 & 7)) << 3)];
            short8 b1 = *(const short8*)&wb[((32 + l31) << 6) + ((jb ^ (l31 & 7)) << 3)];
            uint4 au0, au1;
            au0.x = packbf(zf0 * hf[0][c * 8 + 0], zf0 * hf[0][c * 8 + 1]);
            au0.y = packbf(zf0 * hf[0][c * 8 + 2], zf0 * hf[0][c * 8 + 3]);
            au0.z = packbf(zf0 * hf[0][c * 8 + 4], zf0 * hf[0][c * 8 + 5]);
            au0.w = packbf(zf0 * hf[0][c * 8 + 6], zf0 * hf[0][c * 8 + 7]);
            au1.x = packbf(zf1 * hf[1][c * 8 + 0], zf1 * hf[1][c * 8 + 1]);
            au1.y = packbf(zf1 * hf[1][c * 8 + 2], zf1 * hf[1][c * 8 + 3]);
            au1.z = packbf(zf1 * hf[1][c * 8 + 4], zf1 * hf[1][c * 8 + 5]);
            au1.w = packbf(zf1 * hf[1][c * 8 + 6], zf1 * hf[1][c * 8 + 7]);
            short8 a0 = __builtin_bit_cast(short8, au0);
            short8 a1 = __builtin_bit_cast(short8, au1);
            acc00 = __builtin_amdgcn_mfma_f32_32x32x16_bf16(a0, b0, acc00, 0, 0, 0);
            acc01 = __builtin_amdgcn_mfma_f32_32x32x16_bf16(a0, b1, acc01, 0, 0, 0);
            acc10 = __builtin_amdgcn_mfma_f32_32x32x16_bf16(a1, b0, acc10, 0, 0, 0);
            acc11 = __builtin_amdgcn_mfma_f32_32x32x16_bf16(a1, b1, acc11, 0, 0, 0);
        }
    }

    // epilogue: D row = (r&3)+8*(r>>2)+4*lhi (edge-local), col = i (coalesced)
    #pragma unroll
    for (int r = 0; r < 16; r++) {
        int roff = (r & 3) + 8 * (r >> 2) + 4 * lhi;
        int d0 = sdst[wave * 64 + roff];
        int d1 = sdst[wave * 64 + 32 + roff];
        atomicAdd(m_agg + d0 * 64 + l31,      acc00[r]);
        atomicAdd(m_agg + d0 * 64 + 32 + l31, acc01[r]);
        atomicAdd(m_agg + d1 * 64 + l31,      acc10[r]);
        atomicAdd(m_agg + d1 * 64 + 32 + l31, acc11[r]);
    }
}

// ---- MFMA GRU: [50000, 128]([m|h]) x [128, 256](r,z,in,hn), gates fused in epilogue ----
__global__ __launch_bounds__(256, 2)
void k_gru(const float* __restrict__ magg, const float* __restrict__ h,
           const ushort* __restrict__ hb, const ushort* __restrict__ Bg,
           const float* __restrict__ b_ih, const float* __restrict__ b_hh,
           float* __restrict__ h_out, ushort* __restrict__ hb_out) {
    __shared__ __align__(16) ushort blds[256 * 128];  // 64 KB, XOR-swizzled slots
    int t = threadIdx.x;
    int wave = t >> 6, lane = t & 63, l31 = lane & 31, lhi = lane >> 5;
    for (int idx = t; idx < 4096; idx += 256) {       // 4096 slots of 16B
        int n = idx >> 4, p = idx & 15;
        int ssrc = p ^ (n & 15);
        *(uint4*)&blds[idx * 8] = *(const uint4*)&Bg[n * 128 + ssrc * 8];
    }
    int node0 = blockIdx.x * 128 + wave * 32;
    int m = node0 + l31;
    int mc = (m < NN) ? m : NN - 1;
    short8 afr[8];
    const float* mrow = magg + (size_t)mc * 64;
    #pragma unroll
    for (int ks = 0; ks < 4; ks++) {
        float4 v0 = *(const float4*)(mrow + ks * 16 + lhi * 8);
        float4 v1 = *(const float4*)(mrow + ks * 16 + lhi * 8 + 4);
        uint4 u;
        u.x = pack2rne(v0.x, v0.y); u.y = pack2rne(v0.z, v0.w);
        u.z = pack2rne(v1.x, v1.y); u.w = pack2rne(v1.z, v1.w);
        afr[ks] = __builtin_bit_cast(short8, u);
    }
    const ushort* hrow = hb + (size_t)mc * 64;
    #pragma unroll
    for (int ks = 4; ks < 8; ks++) {
        uint4 v = *(const uint4*)(hrow + (ks - 4) * 16 + lhi * 8);
        afr[ks] = __builtin_bit_cast(short8, v);
    }
    __syncthreads();
    #pragma unroll
    for (int ct = 0; ct < 2; ct++) {
        f32x16 aR = {0}, aZ = {0}, aI = {0}, aH = {0};
        int nR = 0   + ct * 32 + l31;
        int nZ = 64  + ct * 32 + l31;
        int nI = 128 + ct * 32 + l31;
        int nH = 192 + ct * 32 + l31;
        #pragma unroll
        for (int ks = 0; ks < 8; ks++) {
            int s = ks * 2 + lhi;
            short8 a = afr[ks];
            short8 bR = *(const short8*)&blds[nR * 128 + (s ^ (nR & 15)) * 8];
            short8 bZ = *(const short8*)&blds[nZ * 128 + (s ^ (nZ & 15)) * 8];
            short8 bI = *(const short8*)&blds[nI * 128 + (s ^ (nI & 15)) * 8];
            short8 bH = *(const short8*)&blds[nH * 128 + (s ^ (nH & 15)) * 8];
            aR = __builtin_amdgcn_mfma_f32_32x32x16_bf16(a, bR, aR, 0, 0, 0);
            aZ = __builtin_amdgcn_mfma_f32_32x32x16_bf16(a, bZ, aZ, 0, 0, 0);
            aI = __builtin_amdgcn_mfma_f32_32x32x16_bf16(a, bI, aI, 0, 0, 0);
            aH = __builtin_amdgcn_mfma_f32_32x32x16_bf16(a, bH, aH, 0, 0, 0);
        }
        int i = ct * 32 + l31;
        float brv = b_ih[i] + b_hh[i];
        float bzv = b_ih[64 + i] + b_hh[64 + i];
        float biv = b_ih[128 + i];
        float bhv = b_hh[128 + i];
        #pragma unroll
        for (int r = 0; r < 16; r++) {
            int row = (r & 3) + 8 * (r >> 2) + 4 * lhi;
            int node = node0 + row;
            if (node < NN) {
                float ho = h[node * 64 + i];
                float rg = fsigmoid(aR[r] + brv);
                float zg = fsigmoid(aZ[r] + bzv);
                float ng = ftanh(aI[r] + biv + rg * (aH[r] + bhv));
                float hv = (1.f - zg) * ng + zg * ho;
                h_out[node * 64 + i] = hv;
                hb_out[node * 64 + i] = f2bf(hv);
            }
        }
    }
}

// ---- readout scatter: batch sorted -> run-length accumulate ----
__global__ __launch_bounds__(256)
void k_scatter_g(const float* __restrict__ h, const int* __restrict__ batch,
                 float* __restrict__ g) {
    int t = threadIdx.x;
    int i = t & 63, sub = t >> 6;
    int n0 = blockIdx.x * 64 + sub * 16;
    if (n0 >= NN) return;
    float acc = 0.f;
    int curg = batch[n0];
    for (int q = 0; q < 16; q++) {
        int n = n0 + q;
        if (n >= NN) break;
        int gq = batch[n];                 // wave-uniform
        if (gq != curg) {
            atomicAdd(&g[curg * 64 + i], acc);
            acc = 0.f; curg = gq;
        }
        acc += h[n * 64 + i];
    }
    atomicAdd(&g[curg * 64 + i], acc);
}

__global__ __launch_bounds__(1024)
void k_readout(const float* __restrict__ g, const float* __restrict__ W1, const float* __restrict__ b1,
               const float* __restrict__ W2, const float* __restrict__ b2, float* __restrict__ out) {
    __shared__ float gs[64 * 64];
    __shared__ float ts[64 * 64];
    int t = threadIdx.x;
    for (int idx = t; idx < 4096; idx += 1024) gs[idx] = g[idx];
    __syncthreads();
    for (int idx = t; idx < 4096; idx += 1024) {
        int r = idx >> 6, c = idx & 63;
        float acc = b1[c];
        #pragma unroll 8
        for (int k = 0; k < 64; k++) acc += gs[r * 64 + k] * W1[k * 64 + c];
        ts[idx] = fmaxf(acc, 0.f);
    }
    __syncthreads();
    for (int idx = t; idx < 2048; idx += 1024) {
        int r = idx >> 5, c = idx & 31;
        float acc = b2[c];
        #pragma unroll 8
        for (int k = 0; k < 64; k++) acc += ts[r * 64 + k] * W2[k * 32 + c];
        out[idx] = acc;
    }
}

extern "C" void kernel_launch(void* const* d_in, const int* in_sizes, int n_in,
                              void* d_out, int out_size, void* d_ws, size_t ws_size,
                              hipStream_t stream) {
    const float* x     = (const float*)d_in[0];
    const int*   ei    = (const int*)  d_in[1];
    const float* ea    = (const float*)d_in[2];
    const int*   batch = (const int*)  d_in[3];
    const float* W_enc = (const float*)d_in[4];
    const float* b_enc = (const float*)d_in[5];
    const float* W_e1  = (const float*)d_in[6];
    const float* b_e1  = (const float*)d_in[7];
    const float* W_e2  = (const float*)d_in[8];
    const float* b_e2  = (const float*)d_in[9];
    const float* W_ih  = (const float*)d_in[10];
    const float* W_hh  = (const float*)d_in[11];
    const float* b_ih  = (const float*)d_in[12];
    const float* b_hh  = (const float*)d_in[13];
    const float* W_r1  = (const float*)d_in[14];
    const float* b_r1  = (const float*)d_in[15];
    const float* W_r2  = (const float*)d_in[16];
    const float* b_r2  = (const float*)d_in[17];
    float* out = (float*)d_out;

    float* ws    = (float*)d_ws;
    float* h     = ws;                        // NN*64 fp32
    float* h2    = h    + NN * 64;            // NN*64 fp32
    float* magg  = h2   + NN * 64;            // NN*64 fp32
    float* g     = magg + NN * 64;            // NG*64 fp32
    ushort* hb   = (ushort*)(g + NG * 64);    // NN*64 bf16
    ushort* hb2  = hb   + NN * 64;            // NN*64 bf16
    ushort* zbT  = hb2  + NN * 64;            // 65*NE bf16
    ushort* Wtb  = zbT  + (size_t)ZK * NE;    // 65*4096 bf16
    ushort* Bgru = Wtb  + ZK * 4096;          // 256*128 bf16

    hipLaunchKernelGGL(k_prep, dim3((PREP_S0 + PREP_S1 + 255) / 256), dim3(256), 0, stream,
                       W_e2, b_e2, W_ih, W_hh, Wtb, Bgru);
    hipLaunchKernelGGL(k_enc_edge, dim3(NBENC + NBEDG), dim3(256), 0, stream,
                       x, W_enc, b_enc, ea, W_e1, b_e1, h, hb, zbT);

    float* hc = h;    float* hn = h2;
    ushort* hbc = hb; ushort* hbn = hb2;
    for (int s = 0; s < 3; s++) {
        hipMemsetAsync(magg, 0, (size_t)NN * 64 * sizeof(float), stream);
        hipLaunchKernelGGL(k_message, dim3((NE + 255) / 256, KPARTS), dim3(256), 0, stream,
                           zbT, hbc, ei, Wtb, magg);
        hipLaunchKernelGGL(k_gru,     dim3((NN + 127) / 128), dim3(256), 0, stream,
                           magg, hc, hbc, Bgru, b_ih, b_hh, hn, hbn);
        float* tf = hc; hc = hn; hn = tf;
        ushort* tb = hbc; hbc = hbn; hbn = tb;
    }

    hipMemsetAsync(g, 0, (size_t)NG * 64 * sizeof(float), stream);
    hipLaunchKernelGGL(k_scatter_g, dim3((NN + 63) / 64), dim3(256), 0, stream, hc, batch, g);
    hipLaunchKernelGGL(k_readout,   dim3(1), dim3(1024), 0, stream, g, W_r1, b_r1, W_r2, b_r2, out);
}

// Round 9
// 447.806 us; speedup vs baseline: 1.7636x; 1.7636x over previous
//
#include <hip/hip_runtime.h>
#include <hip/hip_bf16.h>
#include <math.h>

#define NN 50000
#define NE 100000
#define FN 128
#define FE 16
#define HD 64
#define OUTD 32
#define NG 64
#define ZK 65           // 64 edge-MLP features + 1 bias slot (z=1)

typedef unsigned int uint;
typedef unsigned short ushort;
typedef __attribute__((ext_vector_type(8))) short short8;
typedef __attribute__((ext_vector_type(16))) float f32x16;

static __device__ __forceinline__ float bfbits2f(uint u) {
    return __builtin_bit_cast(float, u << 16);
}
// one v_perm_b32: result = (hi16(f1)<<16) | hi16(f0)   (truncation pack)
static __device__ __forceinline__ uint packbf(float f0, float f1) {
    return __builtin_amdgcn_perm(__builtin_bit_cast(uint, f1),
                                 __builtin_bit_cast(uint, f0), 0x07060302u);
}
static __device__ __forceinline__ ushort f2bf(float f) {
    uint u = __builtin_bit_cast(uint, f);
    u = (u + 0x7FFFu + ((u >> 16) & 1u)) >> 16;   // RNE
    return (ushort)u;
}
static __device__ __forceinline__ uint pack2rne(float f0, float f1) {
    return (uint)f2bf(f0) | ((uint)f2bf(f1) << 16);
}
static __device__ __forceinline__ float fsigmoid(float x) {
    return 1.f / (1.f + __expf(-x));
}
static __device__ __forceinline__ float ftanh(float x) {
    float t = __expf(2.f * x);
    return 1.f - 2.f / (t + 1.f);
}

// ---- prep: Wtb (message B, k0-blocked) + Bgru ----
#define PREP_S0 (ZK * 4096)
#define PREP_S1 (256 * 128)
__global__ void k_prep(const float* __restrict__ W_e2, const float* __restrict__ b_e2,
                       const float* __restrict__ W_ih, const float* __restrict__ W_hh,
                       ushort* __restrict__ Wtb, ushort* __restrict__ Bg) {
    int idx = blockIdx.x * 256 + threadIdx.x;
    if (idx < PREP_S0) {
        int k0 = idx >> 12, r = idx & 4095;
        int i = r >> 6, j = r & 63;
        float v = (k0 < 64) ? W_e2[k0 * 4096 + i * 64 + j] : b_e2[i * 64 + j];
        Wtb[idx] = f2bf(v);
        return;
    }
    idx -= PREP_S0;
    if (idx < PREP_S1) {
        int n = idx >> 7, k = idx & 127;
        int g = n >> 6, i = n & 63;
        float v = 0.f;
        if (g == 0)      v = (k < 64) ? W_ih[i * 64 + k]         : W_hh[i * 64 + (k - 64)];
        else if (g == 1) v = (k < 64) ? W_ih[(64 + i) * 64 + k]  : W_hh[(64 + i) * 64 + (k - 64)];
        else if (g == 2) v = (k < 64) ? W_ih[(128 + i) * 64 + k] : 0.f;
        else             v = (k < 64) ? 0.f                      : W_hh[(128 + i) * 64 + (k - 64)];
        Bg[idx] = f2bf(v);
    }
}

// ---- merged encoder + edge-MLP (grid split on blockIdx.x) ----
#define NBENC ((NN + 127) / 128)
#define NBEDG ((NE + 255) / 256)
__global__ __launch_bounds__(256, 2)
void k_enc_edge(const float* __restrict__ x, const float* __restrict__ W_enc,
                const float* __restrict__ b_enc,
                const float* __restrict__ ea, const float* __restrict__ W_e1,
                const float* __restrict__ b_e1,
                float* __restrict__ h, ushort* __restrict__ hb,
                ushort* __restrict__ zbT) {
    int t = threadIdx.x;
    if (blockIdx.x < NBENC) {
        // ---- encoder: h = x @ W_enc + b_enc.  M=50000, K=128, N=64 ----
        __shared__ __align__(16) ushort blds[64 * 128];   // 16 KB, XOR-swizzled slots
        int wave = t >> 6, lane = t & 63, l31 = lane & 31, lhi = lane >> 5;
        for (int idx = t; idx < 1024; idx += 256) {       // 1024 slots of 16B
            int n = idx >> 4, p = idx & 15;
            int ssrc = p ^ (n & 15);
            int kk = ssrc * 8;                            // W_enc[k][n], k=kk..kk+7 -> bf16
            uint4 u;
            u.x = pack2rne(W_enc[(kk + 0) * 64 + n], W_enc[(kk + 1) * 64 + n]);
            u.y = pack2rne(W_enc[(kk + 2) * 64 + n], W_enc[(kk + 3) * 64 + n]);
            u.z = pack2rne(W_enc[(kk + 4) * 64 + n], W_enc[(kk + 5) * 64 + n]);
            u.w = pack2rne(W_enc[(kk + 6) * 64 + n], W_enc[(kk + 7) * 64 + n]);
            *(uint4*)&blds[idx * 8] = u;
        }
        int node0 = blockIdx.x * 128 + wave * 32;
        int m = node0 + l31;
        int mc = (m < NN) ? m : NN - 1;
        short8 afr[8];
        const float* xr = x + (size_t)mc * 128;
        #pragma unroll
        for (int ks = 0; ks < 8; ks++) {
            float4 v0 = *(const float4*)(xr + ks * 16 + lhi * 8);
            float4 v1 = *(const float4*)(xr + ks * 16 + lhi * 8 + 4);
            uint4 u;
            u.x = pack2rne(v0.x, v0.y); u.y = pack2rne(v0.z, v0.w);
            u.z = pack2rne(v1.x, v1.y); u.w = pack2rne(v1.z, v1.w);
            afr[ks] = __builtin_bit_cast(short8, u);
        }
        __syncthreads();
        #pragma unroll
        for (int ct = 0; ct < 2; ct++) {
            f32x16 acc = {0};
            int n = ct * 32 + l31;
            #pragma unroll
            for (int ks = 0; ks < 8; ks++) {
                int sp = (ks * 2 + lhi) ^ (n & 15);
                short8 bf = *(const short8*)&blds[n * 128 + sp * 8];
                acc = __builtin_amdgcn_mfma_f32_32x32x16_bf16(afr[ks], bf, acc, 0, 0, 0);
            }
            int o = ct * 32 + l31;
            float bias = b_enc[o];
            #pragma unroll
            for (int r = 0; r < 16; r++) {
                int row = (r & 3) + 8 * (r >> 2) + 4 * lhi;
                int node = node0 + row;
                if (node < NN) {
                    float v = acc[r] + bias;
                    h[node * 64 + o] = v;
                    hb[node * 64 + o] = f2bf(v);
                }
            }
        }
    } else {
        // ---- edge MLP: one thread per edge, all 64 outputs; zbT[k][e] ----
        __shared__ float Ws[16 * 64];
        __shared__ float b1s[64];
        for (int idx = t; idx < 1024; idx += 256) Ws[idx] = W_e1[idx];
        if (t < 64) b1s[t] = b_e1[t];
        __syncthreads();
        int e = (blockIdx.x - NBENC) * 256 + t;
        int ec = (e < NE) ? e : NE - 1;
        float eav[16];
        const float4* ep = (const float4*)(ea + ec * 16);
        #pragma unroll
        for (int q = 0; q < 4; q++) {
            float4 v = ep[q];
            eav[q * 4 + 0] = v.x; eav[q * 4 + 1] = v.y; eav[q * 4 + 2] = v.z; eav[q * 4 + 3] = v.w;
        }
        if (e >= NE) return;
        #pragma unroll 4
        for (int k = 0; k < 64; k++) {
            float acc = b1s[k];
            #pragma unroll
            for (int f = 0; f < 16; f++) acc += eav[f] * Ws[f * 64 + k];
            zbT[(size_t)k * NE + e] = f2bf(fmaxf(acc, 0.f));
        }
        zbT[(size_t)64 * NE + e] = f2bf(1.0f);
    }
}

// ---- MFMA message kernel: z-tile in LDS, 2-slab double-buffered rounds ----
// R3 formulation (A = bf16(z*h_src), B = W2t[k0] from LDS, C[e][i] -> atomics).
// Prologue: gather h into regs; stage the block's WHOLE z-tile (65x256 bf16, 33KB)
// into LDS (one HBM latency for all k0); stage W slabs {0,1}. Loop: 33 rounds of
// 2 k0; stage next 2 slabs AFTER the barrier so their L2 latency hides under this
// round's compute; z comes from LDS (~120cyc, hidden). ~70KB LDS -> 2 blocks/CU.
__global__ __launch_bounds__(256, 2)
void k_message(const ushort* __restrict__ zbT, const ushort* __restrict__ hb,
               const int* __restrict__ eidx, const ushort* __restrict__ Wtb,
               float* __restrict__ m_agg) {
    __shared__ __align__(16) ushort wlds[2][2 * 4096];   // 2 bufs x 2 slabs (16KB each)
    __shared__ __align__(16) ushort zlds[72 * 256];      // 65 rows + pad (36.9KB)
    __shared__ int sdst[256];

    int t = threadIdx.x;
    int wave = t >> 6, lane = t & 63;
    int l31 = lane & 31, lhi = lane >> 5;
    int eblk = blockIdx.x * 256;
    int e0 = eblk + wave * 64;

    {
        int e = eblk + t; if (e >= NE) e = NE - 1;
        sdst[t] = eidx[NE + e];
    }

    // gather h fragments (fp32 in regs) -- latency overlaps all staging below
    float hf[2][32];
    #pragma unroll
    for (int mt = 0; mt < 2; mt++) {
        int e = e0 + mt * 32 + l31;
        int ec = (e < NE) ? e : NE - 1;
        int s = eidx[ec];
        const ushort* hrow = hb + (size_t)s * 64;
        #pragma unroll
        for (int c = 0; c < 4; c++) {
            uint4 v = *(const uint4*)(hrow + c * 16 + lhi * 8);
            hf[mt][c * 8 + 0] = bfbits2f(v.x & 0xFFFFu); hf[mt][c * 8 + 1] = bfbits2f(v.x >> 16);
            hf[mt][c * 8 + 2] = bfbits2f(v.y & 0xFFFFu); hf[mt][c * 8 + 3] = bfbits2f(v.y >> 16);
            hf[mt][c * 8 + 4] = bfbits2f(v.z & 0xFFFFu); hf[mt][c * 8 + 5] = bfbits2f(v.z >> 16);
            hf[mt][c * 8 + 6] = bfbits2f(v.w & 0xFFFFu); hf[mt][c * 8 + 7] = bfbits2f(v.w >> 16);
        }
    }

    // stage z-tile: rows k0=0..64, 512B each; slot s(16B): k0=s>>5, chunk p=s&31.
    // 2080 real slots, rounded to 2304 (full waves; extras land in pad rows).
    #pragma unroll
    for (int call = 0; call < 9; call++) {
        int slot = call * 256 + t;
        int k0 = slot >> 5; if (k0 > 64) k0 = 64;     // clamp source; pad rows unused
        int p = slot & 31;
        const ushort* src = zbT + (size_t)k0 * NE + eblk + p * 8;
        __builtin_amdgcn_global_load_lds(
            (const __attribute__((address_space(1))) void*)src,
            (__attribute__((address_space(3))) void*)&zlds[(size_t)(call * 256 + wave * 64) * 8],
            16, 0, 0);
    }

    // W slab staging: one buffer = 2 slabs = 1024 slots of 16B (4 calls)
    auto stagew = [&](int slab0, int buf) {
        #pragma unroll
        for (int call = 0; call < 4; call++) {
            int slot = call * 256 + t;
            int slab = slab0 + (slot >> 9);
            if (slab > 64) slab = 64;                 // clamp (last round: 1 real slab)
            int w = slot & 511;
            int i = w >> 3, jbp = w & 7;
            int jbg = jbp ^ (i & 7);
            const ushort* src = Wtb + (size_t)slab * 4096 + i * 64 + jbg * 8;
            __builtin_amdgcn_global_load_lds(
                (const __attribute__((address_space(1))) void*)src,
                (__attribute__((address_space(3))) void*)&wlds[buf][(size_t)(call * 256 + wave * 64) * 8],
                16, 0, 0);
        }
    };
    stagew(0, 0);

    f32x16 acc00 = {0}, acc01 = {0}, acc10 = {0}, acc11 = {0};

    for (int rnd = 0; rnd < 33; rnd++) {
        __syncthreads();                              // buf rnd&1 + (rnd==0: z-tile) ready
        int buf = rnd & 1;
        if (rnd < 32) stagew(2 * rnd + 2, buf ^ 1);   // hides under this round's compute
        int nk = (rnd < 32) ? 2 : 1;
        #pragma unroll 2
        for (int kk = 0; kk < nk; kk++) {
            int k0 = 2 * rnd + kk;
            // z from LDS (bf16): row k0, edge-local col
            float zf0 = bfbits2f((uint)zlds[k0 * 256 + wave * 64 + l31]);
            float zf1 = bfbits2f((uint)zlds[k0 * 256 + wave * 64 + 32 + l31]);
            const ushort* wb = &wlds[buf][kk * 4096];
            #pragma unroll
            for (int c = 0; c < 4; c++) {
                int jb = c * 2 + lhi;
                short8 b0 = *(const short8*)&wb[((0 * 32 + l31) << 6) + ((jb ^ (l31 & 7)) << 3)];
                short8 b1 = *(const short8*)&wb[((32 + l31) << 6) + ((jb ^ (l31 & 7)) << 3)];
                uint4 au0, au1;
                au0.x = packbf(zf0 * hf[0][c * 8 + 0], zf0 * hf[0][c * 8 + 1]);
                au0.y = packbf(zf0 * hf[0][c * 8 + 2], zf0 * hf[0][c * 8 + 3]);
                au0.z = packbf(zf0 * hf[0][c * 8 + 4], zf0 * hf[0][c * 8 + 5]);
                au0.w = packbf(zf0 * hf[0][c * 8 + 6], zf0 * hf[0][c * 8 + 7]);
                au1.x = packbf(zf1 * hf[1][c * 8 + 0], zf1 * hf[1][c * 8 + 1]);
                au1.y = packbf(zf1 * hf[1][c * 8 + 2], zf1 * hf[1][c * 8 + 3]);
                au1.z = packbf(zf1 * hf[1][c * 8 + 4], zf1 * hf[1][c * 8 + 5]);
                au1.w = packbf(zf1 * hf[1][c * 8 + 6], zf1 * hf[1][c * 8 + 7]);
                short8 a0 = __builtin_bit_cast(short8, au0);
                short8 a1 = __builtin_bit_cast(short8, au1);
                acc00 = __builtin_amdgcn_mfma_f32_32x32x16_bf16(a0, b0, acc00, 0, 0, 0);
                acc01 = __builtin_amdgcn_mfma_f32_32x32x16_bf16(a0, b1, acc01, 0, 0, 0);
                acc10 = __builtin_amdgcn_mfma_f32_32x32x16_bf16(a1, b0, acc10, 0, 0, 0);
                acc11 = __builtin_amdgcn_mfma_f32_32x32x16_bf16(a1, b1, acc11, 0, 0, 0);
            }
        }
    }

    // epilogue: D row = (r&3)+8*(r>>2)+4*lhi (edge-local), col = i (coalesced).
    // Guard e<NE: invalid-edge lanes carry garbage (z-tile tail reads past NE).
    #pragma unroll
    for (int r = 0; r < 16; r++) {
        int roff = (r & 3) + 8 * (r >> 2) + 4 * lhi;
        int eA = e0 + roff, eB = e0 + 32 + roff;
        if (eA < NE) {
            int d0 = sdst[wave * 64 + roff];
            atomicAdd(m_agg + d0 * 64 + l31,      acc00[r]);
            atomicAdd(m_agg + d0 * 64 + 32 + l31, acc01[r]);
        }
        if (eB < NE) {
            int d1 = sdst[wave * 64 + 32 + roff];
            atomicAdd(m_agg + d1 * 64 + l31,      acc10[r]);
            atomicAdd(m_agg + d1 * 64 + 32 + l31, acc11[r]);
        }
    }
}

// ---- MFMA GRU: [50000, 128]([m|h]) x [128, 256](r,z,in,hn), gates fused in epilogue ----
__global__ __launch_bounds__(256, 2)
void k_gru(const float* __restrict__ magg, const float* __restrict__ h,
           const ushort* __restrict__ hb, const ushort* __restrict__ Bg,
           const float* __restrict__ b_ih, const float* __restrict__ b_hh,
           float* __restrict__ h_out, ushort* __restrict__ hb_out) {
    __shared__ __align__(16) ushort blds[256 * 128];  // 64 KB, XOR-swizzled slots
    int t = threadIdx.x;
    int wave = t >> 6, lane = t & 63, l31 = lane & 31, lhi = lane >> 5;
    for (int idx = t; idx < 4096; idx += 256) {       // 4096 slots of 16B
        int n = idx >> 4, p = idx & 15;
        int ssrc = p ^ (n & 15);
        *(uint4*)&blds[idx * 8] = *(const uint4*)&Bg[n * 128 + ssrc * 8];
    }
    int node0 = blockIdx.x * 128 + wave * 32;
    int m = node0 + l31;
    int mc = (m < NN) ? m : NN - 1;
    short8 afr[8];
    const float* mrow = magg + (size_t)mc * 64;
    #pragma unroll
    for (int ks = 0; ks < 4; ks++) {
        float4 v0 = *(const float4*)(mrow + ks * 16 + lhi * 8);
        float4 v1 = *(const float4*)(mrow + ks * 16 + lhi * 8 + 4);
        uint4 u;
        u.x = pack2rne(v0.x, v0.y); u.y = pack2rne(v0.z, v0.w);
        u.z = pack2rne(v1.x, v1.y); u.w = pack2rne(v1.z, v1.w);
        afr[ks] = __builtin_bit_cast(short8, u);
    }
    const ushort* hrow = hb + (size_t)mc * 64;
    #pragma unroll
    for (int ks = 4; ks < 8; ks++) {
        uint4 v = *(const uint4*)(hrow + (ks - 4) * 16 + lhi * 8);
        afr[ks] = __builtin_bit_cast(short8, v);
    }
    __syncthreads();
    #pragma unroll
    for (int ct = 0; ct < 2; ct++) {
        f32x16 aR = {0}, aZ = {0}, aI = {0}, aH = {0};
        int nR = 0   + ct * 32 + l31;
        int nZ = 64  + ct * 32 + l31;
        int nI = 128 + ct * 32 + l31;
        int nH = 192 + ct * 32 + l31;
        #pragma unroll
        for (int ks = 0; ks < 8; ks++) {
            int s = ks * 2 + lhi;
            short8 a = afr[ks];
            short8 bR = *(const short8*)&blds[nR * 128 + (s ^ (nR & 15)) * 8];
            short8 bZ = *(const short8*)&blds[nZ * 128 + (s ^ (nZ & 15)) * 8];
            short8 bI = *(const short8*)&blds[nI * 128 + (s ^ (nI & 15)) * 8];
            short8 bH = *(const short8*)&blds[nH * 128 + (s ^ (nH & 15)) * 8];
            aR = __builtin_amdgcn_mfma_f32_32x32x16_bf16(a, bR, aR, 0, 0, 0);
            aZ = __builtin_amdgcn_mfma_f32_32x32x16_bf16(a, bZ, aZ, 0, 0, 0);
            aI = __builtin_amdgcn_mfma_f32_32x32x16_bf16(a, bI, aI, 0, 0, 0);
            aH = __builtin_amdgcn_mfma_f32_32x32x16_bf16(a, bH, aH, 0, 0, 0);
        }
        int i = ct * 32 + l31;
        float brv = b_ih[i] + b_hh[i];
        float bzv = b_ih[64 + i] + b_hh[64 + i];
        float biv = b_ih[128 + i];
        float bhv = b_hh[128 + i];
        #pragma unroll
        for (int r = 0; r < 16; r++) {
            int row = (r & 3) + 8 * (r >> 2) + 4 * lhi;
            int node = node0 + row;
            if (node < NN) {
                float ho = h[node * 64 + i];
                float rg = fsigmoid(aR[r] + brv);
                float zg = fsigmoid(aZ[r] + bzv);
                float ng = ftanh(aI[r] + biv + rg * (aH[r] + bhv));
                float hv = (1.f - zg) * ng + zg * ho;
                h_out[node * 64 + i] = hv;
                hb_out[node * 64 + i] = f2bf(hv);
            }
        }
    }
}

// ---- readout scatter: batch sorted -> run-length accumulate ----
__global__ __launch_bounds__(256)
void k_scatter_g(const float* __restrict__ h, const int* __restrict__ batch,
                 float* __restrict__ g) {
    int t = threadIdx.x;
    int i = t & 63, sub = t >> 6;
    int n0 = blockIdx.x * 64 + sub * 16;
    if (n0 >= NN) return;
    float acc = 0.f;
    int curg = batch[n0];
    for (int q = 0; q < 16; q++) {
        int n = n0 + q;
        if (n >= NN) break;
        int gq = batch[n];                 // wave-uniform
        if (gq != curg) {
            atomicAdd(&g[curg * 64 + i], acc);
            acc = 0.f; curg = gq;
        }
        acc += h[n * 64 + i];
    }
    atomicAdd(&g[curg * 64 + i], acc);
}

__global__ __launch_bounds__(1024)
void k_readout(const float* __restrict__ g, const float* __restrict__ W1, const float* __restrict__ b1,
               const float* __restrict__ W2, const float* __restrict__ b2, float* __restrict__ out) {
    __shared__ float gs[64 * 64];
    __shared__ float ts[64 * 64];
    int t = threadIdx.x;
    for (int idx = t; idx < 4096; idx += 1024) gs[idx] = g[idx];
    __syncthreads();
    for (int idx = t; idx < 4096; idx += 1024) {
        int r = idx >> 6, c = idx & 63;
        float acc = b1[c];
        #pragma unroll 8
        for (int k = 0; k < 64; k++) acc += gs[r * 64 + k] * W1[k * 64 + c];
        ts[idx] = fmaxf(acc, 0.f);
    }
    __syncthreads();
    for (int idx = t; idx < 2048; idx += 1024) {
        int r = idx >> 5, c = idx & 31;
        float acc = b2[c];
        #pragma unroll 8
        for (int k = 0; k < 64; k++) acc += ts[r * 64 + k] * W2[k * 32 + c];
        out[idx] = acc;
    }
}

extern "C" void kernel_launch(void* const* d_in, const int* in_sizes, int n_in,
                              void* d_out, int out_size, void* d_ws, size_t ws_size,
                              hipStream_t stream) {
    const float* x     = (const float*)d_in[0];
    const int*   ei    = (const int*)  d_in[1];
    const float* ea    = (const float*)d_in[2];
    const int*   batch = (const int*)  d_in[3];
    const float* W_enc = (const float*)d_in[4];
    const float* b_enc = (const float*)d_in[5];
    const float* W_e1  = (const float*)d_in[6];
    const float* b_e1  = (const float*)d_in[7];
    const float* W_e2  = (const float*)d_in[8];
    const float* b_e2  = (const float*)d_in[9];
    const float* W_ih  = (const float*)d_in[10];
    const float* W_hh  = (const float*)d_in[11];
    const float* b_ih  = (const float*)d_in[12];
    const float* b_hh  = (const float*)d_in[13];
    const float* W_r1  = (const float*)d_in[14];
    const float* b_r1  = (const float*)d_in[15];
    const float* W_r2  = (const float*)d_in[16];
    const float* b_r2  = (const float*)d_in[17];
    float* out = (float*)d_out;

    float* ws    = (float*)d_ws;
    float* h     = ws;                        // NN*64 fp32
    float* h2    = h    + NN * 64;            // NN*64 fp32
    float* magg  = h2   + NN * 64;            // NN*64 fp32
    float* g     = magg + NN * 64;            // NG*64 fp32
    ushort* hb   = (ushort*)(g + NG * 64);    // NN*64 bf16
    ushort* hb2  = hb   + NN * 64;            // NN*64 bf16
    ushort* zbT  = hb2  + NN * 64;            // 65*NE bf16
    ushort* Wtb  = zbT  + (size_t)ZK * NE;    // 65*4096 bf16
    ushort* Bgru = Wtb  + ZK * 4096;          // 256*128 bf16

    hipLaunchKernelGGL(k_prep, dim3((PREP_S0 + PREP_S1 + 255) / 256), dim3(256), 0, stream,
                       W_e2, b_e2, W_ih, W_hh, Wtb, Bgru);
    hipLaunchKernelGGL(k_enc_edge, dim3(NBENC + NBEDG), dim3(256), 0, stream,
                       x, W_enc, b_enc, ea, W_e1, b_e1, h, hb, zbT);

    float* hc = h;    float* hn = h2;
    ushort* hbc = hb; ushort* hbn = hb2;
    for (int s = 0; s < 3; s++) {
        hipMemsetAsync(magg, 0, (size_t)NN * 64 * sizeof(float), stream);
        hipLaunchKernelGGL(k_message, dim3((NE + 255) / 256), dim3(256), 0, stream,
                           zbT, hbc, ei, Wtb, magg);
        hipLaunchKernelGGL(k_gru,     dim3((NN + 127) / 128), dim3(256), 0, stream,
                           magg, hc, hbc, Bgru, b_ih, b_hh, hn, hbn);
        float* tf = hc; hc = hn; hn = tf;
        ushort* tb = hbc; hbc = hbn; hbn = tb;
    }

    hipMemsetAsync(g, 0, (size_t)NG * 64 * sizeof(float), stream);
    hipLaunchKernelGGL(k_scatter_g, dim3((NN + 63) / 64), dim3(256), 0, stream, hc, batch, g);
    hipLaunchKernelGGL(k_readout,   dim3(1), dim3(1024), 0, stream, g, W_r1, b_r1, W_r2, b_r2, out);
}